// Round 2
// baseline (3190.240 us; speedup 1.0000x reference)
//
#include <hip/hip_runtime.h>
#include <math.h>

#define BB 2
#define SS 2048
#define TT 2048
#define DD 256
#define HH 8
#define DHH 32
#define FFF 2048
#define VOC 25426

// ---------------- prep: tgt ids, embedding + 2x + positional enc, pad flags ----------------
__global__ __launch_bounds__(256) void k_prep(const int* __restrict__ tgt_in,
                                              const float* __restrict__ emb,
                                              float* __restrict__ X,
                                              int* __restrict__ pad,
                                              float* __restrict__ out_ids) {
  int r = blockIdx.x;            // 0..B*T-1
  int d = threadIdx.x;           // 0..255
  int b = r / TT, t = r % TT;
  int id = (t == 0) ? VOC : tgt_in[b * (TT - 1) + (t - 1)];
  // pe: even d -> sin(t * 10000^{-d/D}); odd d -> cos with same freq as d-1
  float div = __expf(-(float)(d & ~1) * 0.03597789207803197f);  // ln(10000)/256
  float ang = (float)t * div;
  float pe = (d & 1) ? cosf(ang) : sinf(ang);
  X[(size_t)r * DD + d] = 2.0f * emb[(size_t)id * DD + d] + pe;
  if (d == 0) {
    pad[r] = (id != 0) ? 1 : 0;
    out_ids[r] = (float)((t == 0) ? 0 : id);
  }
}

// ---------------- zero padded encoder rows ----------------
__global__ __launch_bounds__(256) void k_mask_enc(const int* __restrict__ src,
                                                  const float* __restrict__ enc_in,
                                                  float* __restrict__ enc) {
  int r = blockIdx.x, d = threadIdx.x;
  enc[(size_t)r * DD + d] = (src[r] != 0) ? enc_in[(size_t)r * DD + d] : 0.0f;
}

// ---------------- generic fp32 tiled GEMM: C = A[M,K] @ B[K,N] (+bias)(+gelu) ----------------
#define GBM 64
#define GBN 64
#define GBK 16
__global__ __launch_bounds__(256) void k_gemm(const float* __restrict__ A,
                                              const float* __restrict__ Bw,
                                              const float* __restrict__ bias,
                                              float* __restrict__ C,
                                              int M, int N, int K, int act) {
  __shared__ float As[GBK][GBM + 1];
  __shared__ float Bs[GBK][GBN];
  int tid = threadIdx.x;
  int tx = tid & 15, ty = tid >> 4;
  int bm = blockIdx.y * GBM, bn = blockIdx.x * GBN;
  float acc[4][4] = {};
  for (int k0 = 0; k0 < K; k0 += GBK) {
#pragma unroll
    for (int i = 0; i < 4; i++) {
      int l = tid + 256 * i;          // 0..1023
      int ra = l >> 4, ca = l & 15;   // A tile 64x16
      As[ca][ra] = A[(size_t)(bm + ra) * K + k0 + ca];
      int rb = l >> 6, cb = l & 63;   // B tile 16x64
      Bs[rb][cb] = (bn + cb < N) ? Bw[(size_t)(k0 + rb) * N + bn + cb] : 0.0f;
    }
    __syncthreads();
#pragma unroll
    for (int kk = 0; kk < GBK; kk++) {
      float a0 = As[kk][ty * 4 + 0], a1 = As[kk][ty * 4 + 1];
      float a2 = As[kk][ty * 4 + 2], a3 = As[kk][ty * 4 + 3];
      float b0 = Bs[kk][tx * 4 + 0], b1 = Bs[kk][tx * 4 + 1];
      float b2 = Bs[kk][tx * 4 + 2], b3 = Bs[kk][tx * 4 + 3];
      acc[0][0] += a0 * b0; acc[0][1] += a0 * b1; acc[0][2] += a0 * b2; acc[0][3] += a0 * b3;
      acc[1][0] += a1 * b0; acc[1][1] += a1 * b1; acc[1][2] += a1 * b2; acc[1][3] += a1 * b3;
      acc[2][0] += a2 * b0; acc[2][1] += a2 * b1; acc[2][2] += a2 * b2; acc[2][3] += a2 * b3;
      acc[3][0] += a3 * b0; acc[3][1] += a3 * b1; acc[3][2] += a3 * b2; acc[3][3] += a3 * b3;
    }
    __syncthreads();
  }
#pragma unroll
  for (int i = 0; i < 4; i++) {
#pragma unroll
    for (int j = 0; j < 4; j++) {
      int row = bm + ty * 4 + i, col = bn + tx * 4 + j;
      if (col < N) {
        float v = acc[i][j] + (bias ? bias[col] : 0.0f);
        if (act == 1) v = 0.5f * v * (1.0f + erff(v * 0.70710678118654752f));
        C[(size_t)row * N + col] = v;
      }
    }
  }
}

// ---------------- flash-style attention: 64 queries per block, 4 threads/query ----------------
__global__ __launch_bounds__(256) void k_flash(const float* __restrict__ Qb,
                                               const float* __restrict__ Kb,
                                               const float* __restrict__ Vb,
                                               float* __restrict__ Ob,
                                               const int* __restrict__ pad,
                                               int Tq, int Tk, int causal) {
  __shared__ float Kt[64][DHH];
  __shared__ float Vt[64][DHH];
  int t = threadIdx.x;
  int qi = t >> 2, sub = t & 3;          // 64 queries x 4 dim-groups of 8
  int qt = blockIdx.x, bh = blockIdx.y;
  int b = bh / HH, h = bh % HH;
  int qg = qt * 64 + qi;
  float qv[8], ov[8];
  const float* qrow = Qb + ((size_t)(b * Tq + qg)) * DD + h * DHH + sub * 8;
#pragma unroll
  for (int j = 0; j < 8; j++) { qv[j] = qrow[j]; ov[j] = 0.0f; }
  float m = -3.0e38f, l = 0.0f;
  int ntiles = causal ? (qt + 1) : (Tk / 64);
  for (int kt = 0; kt < ntiles; kt++) {
    int kb = kt * 64;
#pragma unroll
    for (int i = 0; i < 8; i++) {
      int lidx = t + 256 * i;             // 0..2047
      int rr = lidx >> 5, cc = lidx & 31;
      Kt[rr][cc] = Kb[((size_t)(b * Tk + kb + rr)) * DD + h * DHH + cc];
      Vt[rr][cc] = Vb[((size_t)(b * Tk + kb + rr)) * DD + h * DHH + cc];
    }
    __syncthreads();
    for (int j = 0; j < 64; j++) {
      int kg = kb + j;
      bool valid = true;
      if (causal) valid = (kg <= qg) && (pad[b * Tq + kg] != 0);
      if (valid) {
        float part = 0.0f;
#pragma unroll
        for (int jj = 0; jj < 8; jj++) part += qv[jj] * Kt[j][sub * 8 + jj];
        part += __shfl_xor(part, 1, 4);
        part += __shfl_xor(part, 2, 4);
        float s = part * 0.17677669529663687f;  // 1/sqrt(32)
        float mn = fmaxf(m, s);
        float corr = __expf(m - mn);
        float p = __expf(s - mn);
        l = l * corr + p;
#pragma unroll
        for (int jj = 0; jj < 8; jj++) ov[jj] = ov[jj] * corr + p * Vt[j][sub * 8 + jj];
        m = mn;
      }
    }
    __syncthreads();
  }
  float inv = 1.0f / l;
  float* orow = Ob + ((size_t)(b * Tq + qg)) * DD + h * DHH + sub * 8;
#pragma unroll
  for (int j = 0; j < 8; j++) orow[j] = ov[j] * inv;
}

// ---------------- fused residual add + LayerNorm (row-per-block, D=256) ----------------
__global__ __launch_bounds__(256) void k_add_ln(const float* __restrict__ xin,
                                                const float* __restrict__ delta,
                                                const float* __restrict__ g,
                                                const float* __restrict__ be,
                                                float* __restrict__ out) {
  __shared__ float sb[256];
  int r = blockIdx.x, d = threadIdx.x;
  float v = xin[(size_t)r * DD + d] + delta[(size_t)r * DD + d];
  sb[d] = v;
  __syncthreads();
  for (int s = 128; s > 0; s >>= 1) { if (d < s) sb[d] += sb[d + s]; __syncthreads(); }
  float mean = sb[0] * (1.0f / DD);
  __syncthreads();
  float c = v - mean;
  sb[d] = c * c;
  __syncthreads();
  for (int s = 128; s > 0; s >>= 1) { if (d < s) sb[d] += sb[d + s]; __syncthreads(); }
  float var = sb[0] * (1.0f / DD);
  out[(size_t)r * DD + d] = c * rsqrtf(var + 1e-5f) * g[d] + be[d];
}

extern "C" void kernel_launch(void* const* d_in, const int* in_sizes, int n_in,
                              void* d_out, int out_size, void* d_ws, size_t ws_size,
                              hipStream_t stream) {
  const int*   src    = (const int*)  d_in[0];
  const int*   tgt    = (const int*)  d_in[1];
  const float* enc_in = (const float*)d_in[2];
  const float* emb    = (const float*)d_in[3];
  const float* Wq_s   = (const float*)d_in[4];
  const float* Wk_s   = (const float*)d_in[5];
  const float* Wv_s   = (const float*)d_in[6];
  const float* Wo_s   = (const float*)d_in[7];
  const float* bo_s   = (const float*)d_in[8];
  const float* Wq_c   = (const float*)d_in[9];
  const float* Wk_c   = (const float*)d_in[10];
  const float* Wv_c   = (const float*)d_in[11];
  const float* Wo_c   = (const float*)d_in[12];
  const float* bo_c   = (const float*)d_in[13];
  const float* W1     = (const float*)d_in[14];
  const float* b1     = (const float*)d_in[15];
  const float* W2     = (const float*)d_in[16];
  const float* b2     = (const float*)d_in[17];
  const float* g1     = (const float*)d_in[18];
  const float* be1    = (const float*)d_in[19];
  const float* g2     = (const float*)d_in[20];
  const float* be2    = (const float*)d_in[21];
  const float* g3     = (const float*)d_in[22];
  const float* be3    = (const float*)d_in[23];
  const float* Wf     = (const float*)d_in[24];
  const float* bf     = (const float*)d_in[25];

  float* logits  = (float*)d_out;
  float* out_ids = logits + (size_t)BB * TT * VOC;   // last B*T floats of d_out

  const size_t NTD = (size_t)BB * TT * DD;  // 1,048,576 floats (4 MB)

  // X must survive the final vocab GEMM (which overwrites the logits region),
  // so it is the ONLY large buffer kept in d_ws (4 MB).
  float* X = (float*)d_ws;

  // All other intermediates are dead before the vocab GEMM runs; stage them
  // inside the (417 MB) logits region. Total use: ~54.5 MB, far from out_ids.
  float* Qb  = logits;
  float* Kb  = Qb  + NTD;
  float* Vb  = Kb  + NTD;
  float* XA  = Vb  + NTD;
  float* ENC = XA  + NTD;
  float* HID = ENC + NTD;                    // B*T*FF = 8,388,608 floats (32 MB)
  float* P   = HID;                          // alias: proj temp (HID dead until FFN)
  int*   PAD = (int*)(HID + (size_t)BB * TT * FFF);

  dim3 blk(256);
  const int M = BB * TT;  // 4096

  // 1) embed + PE + tgt-ids output + pad flags; masked encoder
  k_prep<<<dim3(BB * TT), blk, 0, stream>>>(tgt, emb, X, PAD, out_ids);
  k_mask_enc<<<dim3(BB * SS), blk, 0, stream>>>(src, enc_in, ENC);

  // 2) self-attention
  k_gemm<<<dim3(DD / GBN, M / GBM), blk, 0, stream>>>(X, Wq_s, nullptr, Qb, M, DD, DD, 0);
  k_gemm<<<dim3(DD / GBN, M / GBM), blk, 0, stream>>>(X, Wk_s, nullptr, Kb, M, DD, DD, 0);
  k_gemm<<<dim3(DD / GBN, M / GBM), blk, 0, stream>>>(X, Wv_s, nullptr, Vb, M, DD, DD, 0);
  k_flash<<<dim3(TT / 64, BB * HH), blk, 0, stream>>>(Qb, Kb, Vb, XA, PAD, TT, TT, 1);
  k_gemm<<<dim3(DD / GBN, M / GBM), blk, 0, stream>>>(XA, Wo_s, bo_s, P, M, DD, DD, 0);
  k_add_ln<<<dim3(M), blk, 0, stream>>>(X, P, g1, be1, X);

  // 3) cross-attention (keys/values from masked encoder; scores unmasked)
  k_gemm<<<dim3(DD / GBN, M / GBM), blk, 0, stream>>>(X, Wq_c, nullptr, Qb, M, DD, DD, 0);
  k_gemm<<<dim3(DD / GBN, M / GBM), blk, 0, stream>>>(ENC, Wk_c, nullptr, Kb, BB * SS, DD, DD, 0);
  k_gemm<<<dim3(DD / GBN, M / GBM), blk, 0, stream>>>(ENC, Wv_c, nullptr, Vb, BB * SS, DD, DD, 0);
  k_flash<<<dim3(TT / 64, BB * HH), blk, 0, stream>>>(Qb, Kb, Vb, XA, nullptr, TT, SS, 0);
  k_gemm<<<dim3(DD / GBN, M / GBM), blk, 0, stream>>>(XA, Wo_c, bo_c, P, M, DD, DD, 0);
  k_add_ln<<<dim3(M), blk, 0, stream>>>(X, P, g2, be2, X);

  // 4) FFN (exact GELU fused into first GEMM)
  k_gemm<<<dim3(FFF / GBN, M / GBM), blk, 0, stream>>>(X, W1, b1, HID, M, FFF, DD, 1);
  k_gemm<<<dim3(DD / GBN, M / GBM), blk, 0, stream>>>(HID, W2, b2, XA, M, DD, FFF, 0);
  k_add_ln<<<dim3(M), blk, 0, stream>>>(X, XA, g3, be3, X);

  // 5) vocab projection -> logits (dominant dispatch; overwrites scratch region)
  k_gemm<<<dim3((VOC + GBN - 1) / GBN, M / GBM), blk, 0, stream>>>(X, Wf, bf, logits, M, VOC, DD, 0);
}